// Round 5
// baseline (245.084 us; speedup 1.0000x reference)
//
#include <hip/hip_runtime.h>
#include <hip/hip_bf16.h>

#define BN 4
#define CC 256
#define C8 32
#define NN 4096
#define PROJ_ROWS 320
#define LOG2E 1.4426950408889634f

typedef __attribute__((ext_vector_type(8))) short short8;
typedef __attribute__((ext_vector_type(4))) short short4v;
typedef __attribute__((ext_vector_type(4))) float f32x4;
typedef __attribute__((ext_vector_type(2))) unsigned int uint2v;

__device__ __forceinline__ unsigned short f2bf(float f) {
    unsigned u = __builtin_bit_cast(unsigned, f);
    unsigned r = (u + 0x7fffu + ((u >> 16) & 1u)) >> 16;
    return (unsigned short)r;
}

// K=16 bf16 MFMA: D = A*B + C. Crucial property used below: D's lane layout
// (row=lq*4+r, col=l15) equals B's lane layout (k=lq*4+j, col=l15).
__device__ __forceinline__ f32x4 mfma16_bf16(short4v a, short4v b, f32x4 c) {
#if __has_builtin(__builtin_amdgcn_mfma_f32_16x16x16bf16_1k)
    return __builtin_amdgcn_mfma_f32_16x16x16bf16_1k(a, b, c, 0, 0, 0);
#else
    asm("v_mfma_f32_16x16x16_bf16 %0, %1, %2, %0" : "+v"(c) : "v"(a), "v"(b));
    return c;
#endif
}

// ---------------------------------------------------------------------------
// Projection GEMM. Block = (b, 32-wide n-tile), all 320 o-rows; x read once.
// Wk/bk pre-scaled by log2(e) so attn can use exp2 directly.
// Grid: 4*128 = 512 blocks (2 blocks/CU), 256 threads.
// ---------------------------------------------------------------------------
__global__ __launch_bounds__(256) void proj_kernel(
    const float* __restrict__ x,
    const float* __restrict__ Wq, const float* __restrict__ bq,
    const float* __restrict__ Wk, const float* __restrict__ bk,
    const float* __restrict__ Wv, const float* __restrict__ bv,
    unsigned short* __restrict__ proj, unsigned short* __restrict__ qT)
{
    int bid = blockIdx.x;
    int b = bid >> 7, nt = bid & 127;
    int n0 = nt * 32;
    int tid = threadIdx.x;
    int w = tid >> 6, l = tid & 63, l15 = l & 15, lq = l >> 4;

    // Xt[n 32][c 256], stride 264 shorts = 528 B
    __shared__ alignas(16) unsigned short Xt[32][264];

    int c_l = tid >> 3;          // 0..31
    int nb  = (tid & 7) * 4;     // 0..28

#pragma unroll
    for (int kc = 0; kc < 8; kc++) {
        const float* xp = x + ((size_t)(b * CC + kc * 32 + c_l)) * NN + n0 + nb;
        float4 x0 = *(const float4*)xp;
        Xt[nb + 0][kc * 32 + c_l] = f2bf(x0.x);
        Xt[nb + 1][kc * 32 + c_l] = f2bf(x0.y);
        Xt[nb + 2][kc * 32 + c_l] = f2bf(x0.z);
        Xt[nb + 3][kc * 32 + c_l] = f2bf(x0.w);
    }
    __syncthreads();

    f32x4 acc[5][2];   // wave owns o-groups g = 5w..5w+4 (16 rows each), 2 n-tiles
#pragma unroll
    for (int gi = 0; gi < 5; gi++)
#pragma unroll
        for (int mi = 0; mi < 2; mi++) acc[gi][mi] = (f32x4){0.f, 0.f, 0.f, 0.f};

    for (int kc = 0; kc < 8; kc++) {
        float4 wf[5][2];
#pragma unroll
        for (int gi = 0; gi < 5; gi++) {
            int og = (w * 5 + gi) * 16 + l15;
            const float* wrow = (og < 32) ? (Wq + (size_t)og * CC)
                              : (og < 64) ? (Wk + (size_t)(og - 32) * CC)
                                          : (Wv + (size_t)(og - 64) * CC);
            const float* wp = wrow + kc * 32 + lq * 8;
            wf[gi][0] = *(const float4*)wp;
            wf[gi][1] = *(const float4*)(wp + 4);
        }
#pragma unroll
        for (int gi = 0; gi < 5; gi++) {
            unsigned short a8[8] __attribute__((aligned(16)));
            float tw[8] = {wf[gi][0].x, wf[gi][0].y, wf[gi][0].z, wf[gi][0].w,
                           wf[gi][1].x, wf[gi][1].y, wf[gi][1].z, wf[gi][1].w};
#pragma unroll
            for (int e = 0; e < 8; e++) a8[e] = f2bf(tw[e]);
            short8 af = *(const short8*)a8;
#pragma unroll
            for (int mi = 0; mi < 2; mi++) {
                short8 bf = *(const short8*)&Xt[mi * 16 + l15][kc * 32 + lq * 8];
                acc[gi][mi] = __builtin_amdgcn_mfma_f32_16x16x32_bf16(af, bf, acc[gi][mi], 0, 0, 0);
            }
        }
    }

    // epilogue: bias (+ log2e scaling for k rows) + bf16 store.
#pragma unroll
    for (int gi = 0; gi < 5; gi++) {
#pragma unroll
        for (int r = 0; r < 4; r++) {
            int og = (w * 5 + gi) * 16 + lq * 4 + r;
            float bias = (og < 32) ? bq[og] : (og < 64) ? bk[og - 32] : bv[og - 64];
            bool is_k = (og >= 32) && (og < 64);
#pragma unroll
            for (int mi = 0; mi < 2; mi++) {
                int n = n0 + mi * 16 + l15;
                float v = acc[gi][mi][r] + bias;
                if (is_k) v *= LOG2E;
                unsigned short v16 = f2bf(v);
                if (og < 32) {
                    qT[((size_t)b * NN + n) * C8 + og] = v16;
                } else {
                    proj[((size_t)b * PROJ_ROWS + og) * NN + n] = v16;
                }
            }
        }
    }
}

// ---------------------------------------------------------------------------
// Flash attention over the query axis, single-wave blocks (64 threads),
// ZERO LDS, ZERO barriers. Each wave owns (b, 64-m tile, 128-c half, n-split)
// and iterates over 16-n chunks:
//   S (K=32 MFMA, 16n x 64m) -> P = exp2(S) in-register -> PV with K=16
//   MFMAs, exploiting D-layout == B-layout for 16x16x16 (no exchange).
// v/q prefetched one iteration ahead. Softmax has no max subtraction
// (|S| small; shift-invariant) and k is pre-scaled by log2e.
// ---------------------------------------------------------------------------
template<int NSPLIT, bool FINAL>
__global__ __launch_bounds__(64, 2) void attn_kernel(
    const unsigned short* __restrict__ proj,
    const unsigned short* __restrict__ qT,
    const float* __restrict__ x,
    const float* __restrict__ gamma_p,
    float* __restrict__ out,
    float* __restrict__ Opart,
    float* __restrict__ Lpart)
{
    constexpr int ITERS = NN / NSPLIT / 16;
    int bid = blockIdx.x;
    int low = bid & 7;               // XCD id under HW round-robin
    int b = low >> 1, mhalf = low & 1;   // batch pinned to an XCD pair
    int rest = bid >> 3;
    int h  = rest % NSPLIT;
    int ch = (rest / NSPLIT) & 1;
    int mt = ((rest / (NSPLIT * 2)) << 1) | mhalf;
    int m0 = mt * 64;
    int c0 = ch * 128;
    int nbase = h * (NN / NSPLIT);

    int l = threadIdx.x;
    int l15 = l & 15, lq = l >> 4;

    const unsigned short* kbase = proj + ((size_t)b * PROJ_ROWS + C8) * NN;
    const unsigned short* vbase = proj + ((size_t)b * PROJ_ROWS + 64) * NN;
    const unsigned short* qbase = qT + (size_t)b * NN * C8;

    // k B-operand fragments for S (K=32): lane = k[c8=lq*8+j][m=m0+mi*16+l15]
    short8 kfrag[4];
#pragma unroll
    for (int mi = 0; mi < 4; mi++) {
        int col = m0 + mi * 16 + l15;
        unsigned short t8[8] __attribute__((aligned(16)));
#pragma unroll
        for (int j = 0; j < 8; j++)
            t8[j] = kbase[(size_t)(lq * 8 + j) * NN + col];
        kfrag[mi] = *(const short8*)t8;
    }

    f32x4 O[8][4];
#pragma unroll
    for (int ci = 0; ci < 8; ci++)
#pragma unroll
        for (int mi = 0; mi < 4; mi++) O[ci][mi] = (f32x4){0.f, 0.f, 0.f, 0.f};
    float runS[4] = {0.f, 0.f, 0.f, 0.f};

    // prefetch for iteration 0:
    // av[ci]: v A-operand (K=16): lane = V[c=c0+ci*16+l15][n=n0c+lq*4+j], 8 B
    // qfrag:  q A-operand (K=32): lane = Q[n=n0c+l15][c8=lq*8+j], 16 B
    uint2v av[8];
#pragma unroll
    for (int ci = 0; ci < 8; ci++)
        av[ci] = *(const uint2v*)(vbase + (size_t)(c0 + ci * 16 + l15) * NN + nbase + lq * 4);
    short8 qfrag = *(const short8*)(qbase + (size_t)(nbase + l15) * C8 + lq * 8);

    for (int it = 0; it < ITERS; it++) {
        int n0c = nbase + it * 16;

        // prefetch next 16-n chunk (consumed next iteration; latency hidden
        // behind this iteration's S/exp/PV)
        uint2v avn[8];
        short8 qn;
        if (it + 1 < ITERS) {
            int nn = n0c + 16;
#pragma unroll
            for (int ci = 0; ci < 8; ci++)
                avn[ci] = *(const uint2v*)(vbase + (size_t)(c0 + ci * 16 + l15) * NN + nn + lq * 4);
            qn = *(const short8*)(qbase + (size_t)(nn + l15) * C8 + lq * 8);
        }

        // S = Q(16n) . K(64m), K-dim = 32 channels; D: row n=lq*4+r, col m=l15
        f32x4 S[4];
#pragma unroll
        for (int mi = 0; mi < 4; mi++)
            S[mi] = __builtin_amdgcn_mfma_f32_16x16x32_bf16(
                qfrag, kfrag[mi], (f32x4){0.f, 0.f, 0.f, 0.f}, 0, 0, 0);

        // P = exp2(S) (k pre-scaled by log2e). D-layout == B-layout for the
        // K=16 MFMA, so pack in-register; also accumulate column sums.
        short4v pf[4];
#pragma unroll
        for (int mi = 0; mi < 4; mi++) {
            float p0 = exp2f(S[mi][0]);
            float p1 = exp2f(S[mi][1]);
            float p2 = exp2f(S[mi][2]);
            float p3 = exp2f(S[mi][3]);
            runS[mi] += (p0 + p1) + (p2 + p3);
            uint2v u;
            u.x = (unsigned)f2bf(p0) | ((unsigned)f2bf(p1) << 16);
            u.y = (unsigned)f2bf(p2) | ((unsigned)f2bf(p3) << 16);
            pf[mi] = __builtin_bit_cast(short4v, u);
        }

        // PV: O[c,m] += V[c, n16] . P[n16, m]  (K=16 MFMAs)
#pragma unroll
        for (int ci = 0; ci < 8; ci++) {
            short4v a = __builtin_bit_cast(short4v, av[ci]);
#pragma unroll
            for (int mi = 0; mi < 4; mi++)
                O[ci][mi] = mfma16_bf16(a, pf[mi], O[ci][mi]);
        }

        if (it + 1 < ITERS) {
#pragma unroll
            for (int ci = 0; ci < 8; ci++) av[ci] = avn[ci];
            qfrag = qn;
        }
    }

    // column sums over this wave's n-range: reduce across row-quads
#pragma unroll
    for (int mi = 0; mi < 4; mi++) {
        float s = runS[mi];
        s += __shfl_xor(s, 16);
        s += __shfl_xor(s, 32);
        runS[mi] = s;   // L[m = mi*16+l15], all lanes
    }

    if constexpr (FINAL) {
        float gamma = gamma_p[0];
        float iv[4];
#pragma unroll
        for (int mi = 0; mi < 4; mi++) iv[mi] = 1.0f / runS[mi];
#pragma unroll
        for (int ci = 0; ci < 8; ci++) {
#pragma unroll
            for (int mi = 0; mi < 4; mi++) {
                int m = m0 + mi * 16 + l15;
#pragma unroll
                for (int r = 0; r < 4; r++) {
                    int c = c0 + ci * 16 + lq * 4 + r;
                    size_t idx = ((size_t)b * CC + c) * NN + m;
                    out[idx] = gamma * (O[ci][mi][r] * iv[mi]) + x[idx];
                }
            }
        }
    } else {
        size_t p = ((size_t)h * BN + b) * 64 + mt;
        if (ch == 0 && lq == 0) {
#pragma unroll
            for (int mi = 0; mi < 4; mi++)
                Lpart[p * 64 + mi * 16 + l15] = runS[mi];
        }
        float* Ob = Opart + p * (size_t)(CC * 64);
#pragma unroll
        for (int ci = 0; ci < 8; ci++) {
#pragma unroll
            for (int mi = 0; mi < 4; mi++) {
#pragma unroll
                for (int r = 0; r < 4; r++) {
                    int c = c0 + ci * 16 + lq * 4 + r;
                    Ob[c * 64 + mi * 16 + l15] = O[ci][mi][r];
                }
            }
        }
    }
}

// ---------------------------------------------------------------------------
// Combine: out = gamma * (sum_h O_h) / (sum_h L_h) + x.
// Grid 1024: one block per (b, mt, c-quarter).
// ---------------------------------------------------------------------------
template<int NSPLIT>
__global__ __launch_bounds__(256) void combine_kernel(
    const float* __restrict__ Opart, const float* __restrict__ Lpart,
    const float* __restrict__ x, const float* __restrict__ gamma_p,
    float* __restrict__ out)
{
    int bid = blockIdx.x;
    int cq = bid & 3;
    int mt = (bid >> 2) & 63;
    int b  = bid >> 8;
    int tid = threadIdx.x;
    int m4 = tid & 15, c16 = tid >> 4;
    float gamma = gamma_p[0];

    f32x4 Ls = (f32x4){0.f, 0.f, 0.f, 0.f};
#pragma unroll
    for (int h = 0; h < NSPLIT; h++) {
        size_t p = ((size_t)h * BN + b) * 64 + mt;
        Ls += *(const f32x4*)(Lpart + p * 64 + m4 * 4);
    }
    f32x4 inv;
#pragma unroll
    for (int j = 0; j < 4; j++) inv[j] = 1.0f / Ls[j];

#pragma unroll
    for (int cp = 0; cp < 4; cp++) {
        int c = cq * 64 + cp * 16 + c16;
        f32x4 acc = (f32x4){0.f, 0.f, 0.f, 0.f};
#pragma unroll
        for (int h = 0; h < NSPLIT; h++) {
            size_t p = ((size_t)h * BN + b) * 64 + mt;
            acc += *(const f32x4*)(Opart + p * (size_t)(CC * 64) + c * 64 + m4 * 4);
        }
        size_t idx = ((size_t)b * CC + c) * NN + mt * 64 + m4 * 4;
        f32x4 xv = *(const f32x4*)(x + idx);
        f32x4 o;
#pragma unroll
        for (int j = 0; j < 4; j++) o[j] = gamma * (acc[j] * inv[j]) + xv[j];
        *(f32x4*)(out + idx) = o;
    }
}

extern "C" void kernel_launch(void* const* d_in, const int* in_sizes, int n_in,
                              void* d_out, int out_size, void* d_ws, size_t ws_size,
                              hipStream_t stream) {
    const float* x     = (const float*)d_in[0];
    const float* Wq    = (const float*)d_in[1];
    const float* bq    = (const float*)d_in[2];
    const float* Wk    = (const float*)d_in[3];
    const float* bk    = (const float*)d_in[4];
    const float* Wv    = (const float*)d_in[5];
    const float* bv    = (const float*)d_in[6];
    const float* gamma = (const float*)d_in[7];
    float* out = (float*)d_out;
    (void)in_sizes; (void)n_in; (void)out_size;

    unsigned short* proj = (unsigned short*)d_ws;
    unsigned short* qT   = proj + (size_t)BN * PROJ_ROWS * NN;
    const size_t baseB = ((size_t)BN * PROJ_ROWS * NN + (size_t)BN * NN * C8) * 2;

    auto needB = [&](int ns) {
        size_t LpB = (size_t)ns * BN * 64 * 64 * 4;
        size_t OpB = (size_t)ns * BN * 64 * CC * 64 * 4;
        return baseB + LpB + OpB;
    };

    proj_kernel<<<512, 256, 0, stream>>>(x, Wq, bq, Wk, bk, Wv, bv, proj, qT);

    if (ws_size >= needB(4)) {
        float* Lpart = (float*)((char*)d_ws + baseB);
        float* Opart = Lpart + (size_t)4 * BN * 64 * 64;
        attn_kernel<4, false><<<2048, 64, 0, stream>>>(proj, qT, x, gamma, out, Opart, Lpart);
        combine_kernel<4><<<1024, 256, 0, stream>>>(Opart, Lpart, x, gamma, out);
    } else if (ws_size >= needB(2)) {
        float* Lpart = (float*)((char*)d_ws + baseB);
        float* Opart = Lpart + (size_t)2 * BN * 64 * 64;
        attn_kernel<2, false><<<1024, 64, 0, stream>>>(proj, qT, x, gamma, out, Opart, Lpart);
        combine_kernel<2><<<1024, 256, 0, stream>>>(Opart, Lpart, x, gamma, out);
    } else {
        attn_kernel<1, true><<<512, 64, 0, stream>>>(proj, qT, x, gamma, out, nullptr, nullptr);
    }
}